// Round 11
// baseline (161.973 us; speedup 1.0000x reference)
//
#include <hip/hip_runtime.h>
#include <math.h>

// Problem constants (HeadAttention_738734374917)
#define Bn  8
#define Nn  2048
#define Dn  1024
#define DHn 64
#define PAD  72  // LDS row pitch (shorts) for 64-wide tiles
#define PADP 72  // LDS row pitch for Ps bounce

typedef __attribute__((ext_vector_type(8))) short bf16x8;  // 8 bf16 = 4 VGPRs
typedef __attribute__((ext_vector_type(4))) float f32x4;

static __device__ inline short f2bf(float f) {
    unsigned u = __builtin_bit_cast(unsigned, f);
    u += 0x7FFFu + ((u >> 16) & 1u);     // round-to-nearest-even
    return (short)(u >> 16);
}
static __device__ inline float bf2f(short s) {
    unsigned u = ((unsigned)(unsigned short)s) << 16;
    return __builtin_bit_cast(float, u);
}
static __device__ inline bf16x8 pack8(float4 a, float4 b) {
    bf16x8 v;
    v[0] = f2bf(a.x); v[1] = f2bf(a.y); v[2] = f2bf(a.z); v[3] = f2bf(a.w);
    v[4] = f2bf(b.x); v[5] = f2bf(b.y); v[6] = f2bf(b.z); v[7] = f2bf(b.w);
    return v;
}

// ---------------------------------------------------------------------------
// Wt in B-FRAG-MAJOR order: Wtf[ntg 0..11][kt 0..15][half 0..1][lane 0..63][e 0..7]
// ---------------------------------------------------------------------------
__global__ __launch_bounds__(128) void wt_kernel(
    const float* __restrict__ Wq, const float* __restrict__ Wk,
    const float* __restrict__ Wv, short* __restrict__ Wtf)
{
    const int nt = blockIdx.x / 16, kt = blockIdx.x % 16;
    const int t = threadIdx.x;
    const int half = t >> 6, l = t & 63;
    const int c = l & 15, quad = l >> 4;
    const int mat = nt >> 2, cm = (nt & 3) * 16 + c;
    const float* Wm = (mat == 0) ? Wq : (mat == 1 ? Wk : Wv);
    short* o = &Wtf[((((size_t)nt * 16 + kt) * 2 + half) * 64 + l) * 8];
#pragma unroll
    for (int e = 0; e < 8; ++e) {
        const int k = kt * 64 + half * 32 + quad * 8 + e;
        o[e] = f2bf(Wm[(size_t)k * DHn + cm]);
    }
}

// ---------------------------------------------------------------------------
// K1: QKV projection (r10 structure, unchanged): M=32, grid 512, dbuf xs,
// one barrier/kt, frag-major Wtf B-loads.
// Outputs: Qb[i][d], Kb[j][d]*0.125, Vt[b][d][j] — all bf16.
// ---------------------------------------------------------------------------
__global__ __launch_bounds__(256) void qkv_kernel(
    const float* __restrict__ x, const short* __restrict__ Wtf,
    const float* __restrict__ bq, const float* __restrict__ bk,
    const float* __restrict__ bv,
    short* __restrict__ Qb, short* __restrict__ Kb, short* __restrict__ Vt)
{
    __shared__ __attribute__((aligned(16))) short xs[2][32][PAD];

    const int t = threadIdx.x;
    const int w = t >> 6, l = t & 63;
    const int c = l & 15, quad = l >> 4;
    const int ibase = blockIdx.x * 32;
    const int r0 = t >> 3, kc = t & 7;

    const float* xrow = &x[(size_t)(ibase + r0) * Dn + kc * 8];

    {
        const float4 a = ((const float4*)xrow)[0];
        const float4 b = ((const float4*)xrow)[1];
        *(bf16x8*)&xs[0][r0][kc * 8] = pack8(a, b);
    }

    f32x4 acc[2][3];
#pragma unroll
    for (int mt = 0; mt < 2; ++mt)
#pragma unroll
        for (int nt = 0; nt < 3; ++nt) acc[mt][nt] = (f32x4){0.f, 0.f, 0.f, 0.f};

    __syncthreads();

    for (int kt = 0; kt < 16; ++kt) {
        const int cur = kt & 1;
        float4 pa, pb;
        if (kt < 15) {
            pa = ((const float4*)(xrow + (kt + 1) * 64))[0];
            pb = ((const float4*)(xrow + (kt + 1) * 64))[1];
        }
#pragma unroll
        for (int h = 0; h < 2; ++h) {
            const bf16x8 af0 = *(const bf16x8*)&xs[cur][c][h * 32 + quad * 8];
            const bf16x8 af1 = *(const bf16x8*)&xs[cur][16 + c][h * 32 + quad * 8];
#pragma unroll
            for (int nt = 0; nt < 3; ++nt) {
                const int ntg = w * 3 + nt;
                const bf16x8 bf = *(const bf16x8*)&Wtf[((((size_t)ntg * 16 + kt) * 2 + h) * 64 + l) * 8];
                acc[0][nt] = __builtin_amdgcn_mfma_f32_16x16x32_bf16(af0, bf, acc[0][nt], 0, 0, 0);
                acc[1][nt] = __builtin_amdgcn_mfma_f32_16x16x32_bf16(af1, bf, acc[1][nt], 0, 0, 0);
            }
        }
        if (kt < 15) *(bf16x8*)&xs[1 - cur][r0][kc * 8] = pack8(pa, pb);
        __syncthreads();
    }

#pragma unroll
    for (int nt = 0; nt < 3; ++nt) {
        const int col = w * 48 + nt * 16 + c;
        const int mat = col >> 6, cm = col & 63;
        const float bias = (mat == 0 ? bq : (mat == 1 ? bk : bv))[cm];
#pragma unroll
        for (int mt = 0; mt < 2; ++mt) {
            if (mat == 2) {
                const int row = ibase + mt * 16 + quad * 4;
                const int b = row >> 11, i = row & (Nn - 1);
                ushort4 o;
                o.x = (unsigned short)f2bf(acc[mt][nt][0] + bias);
                o.y = (unsigned short)f2bf(acc[mt][nt][1] + bias);
                o.z = (unsigned short)f2bf(acc[mt][nt][2] + bias);
                o.w = (unsigned short)f2bf(acc[mt][nt][3] + bias);
                *(ushort4*)&Vt[((size_t)b * DHn + cm) * Nn + i] = o;
            } else {
                const float s = (mat == 1) ? 0.125f : 1.0f;
                short* Out = (mat == 0) ? Qb : Kb;
#pragma unroll
                for (int r = 0; r < 4; ++r)
                    Out[(size_t)(ibase + mt * 16 + quad * 4 + r) * DHn + cm] =
                        f2bf((acc[mt][nt][r] + bias) * s);
            }
        }
    }
}

// ---------------------------------------------------------------------------
// K2: per (b, j-tile 64, i-split s of 4): lpart[s][b][j] = sum_i exp(S_ij)
// AND materialize E = exp(S) in A-FRAG-MAJOR layout:
//   Eb[b][f=i/16][h=j/32][lane][8]  (lane c holds i=f*16+c, j=h*32+quad*8+e)
// K-frags register-resident; wave-private Q staging (no loop barriers);
// C->A bounce via wave-private Ps, coalesced 1KB frag stores.
// ---------------------------------------------------------------------------
__global__ __launch_bounds__(256) void colsum_kernel(
    const short* __restrict__ Qb, const short* __restrict__ Kb,
    float* __restrict__ lpart, short* __restrict__ Eb)
{
    __shared__ __attribute__((aligned(16))) short Qw[4][2][32][PAD];
    __shared__ __attribute__((aligned(16))) short Ps[4][16][PADP];
    __shared__ float red[16][64];

    const int t = threadIdx.x;
    const int w = t >> 6, l = t & 63;
    const int c = l & 15, quad = l >> 4;
    const int bid = blockIdx.x;
    const int b = bid >> 7, rem = bid & 127, jt = rem >> 2, s = rem & 3;
    const int jbase = jt * 64;
    const int srow = l >> 1, scoff = (l & 1) * 32;   // staging: 32 rows, half-row/lane

    bf16x8 kb[4][2];
#pragma unroll
    for (int nt = 0; nt < 4; ++nt)
#pragma unroll
        for (int kk = 0; kk < 2; ++kk)
            kb[nt][kk] = *(const bf16x8*)&Kb[((size_t)b * Nn + jbase + nt * 16 + c) * DHn
                                             + kk * 32 + quad * 8];

    // wave w owns contiguous 128 i: s*512 + w*128, 4 iters of 32 rows
    const short* qbase = &Qb[((size_t)b * Nn + s * 512 + w * 128 + srow) * DHn + scoff];

#pragma unroll
    for (int k = 0; k < 4; ++k)
        *(bf16x8*)&Qw[w][0][srow][scoff + k * 8] = *(const bf16x8*)(qbase + k * 8);

    float lsum[4] = {0.f, 0.f, 0.f, 0.f};

    for (int it2 = 0; it2 < 4; ++it2) {
        const int cur = it2 & 1;
        bf16x8 p[4];
        if (it2 < 3) {
            const short* pq = qbase + (size_t)(it2 + 1) * 32 * DHn;
#pragma unroll
            for (int k = 0; k < 4; ++k) p[k] = *(const bf16x8*)(pq + k * 8);
        }
        // two 16-row chunks per iter
#pragma unroll
        for (int cc2 = 0; cc2 < 2; ++cc2) {
            const bf16x8 aq0 = *(const bf16x8*)&Qw[w][cur][cc2 * 16 + c][quad * 8];
            const bf16x8 aq1 = *(const bf16x8*)&Qw[w][cur][cc2 * 16 + c][32 + quad * 8];
#pragma unroll
            for (int nt = 0; nt < 4; ++nt) {
                f32x4 sv = (f32x4){0.f, 0.f, 0.f, 0.f};
                sv = __builtin_amdgcn_mfma_f32_16x16x32_bf16(aq0, kb[nt][0], sv, 0, 0, 0);
                sv = __builtin_amdgcn_mfma_f32_16x16x32_bf16(aq1, kb[nt][1], sv, 0, 0, 0);
#pragma unroll
                for (int r = 0; r < 4; ++r) {
                    const float e = __expf(sv[r]);
                    lsum[nt] += e;
                    Ps[w][quad * 4 + r][nt * 16 + c] = f2bf(e);   // C->A bounce
                }
            }
            // read back in A-layout, store coalesced frag to Eb
            const int f = s * 32 + w * 8 + it2 * 2 + cc2;   // global i-frag
            const bf16x8 ap0 = *(const bf16x8*)&Ps[w][c][quad * 8];
            const bf16x8 ap1 = *(const bf16x8*)&Ps[w][c][32 + quad * 8];
            short* eb = &Eb[((((size_t)b * 128 + f) * 64) + jt * 2) * 512 + l * 8];
            *(bf16x8*)eb         = ap0;
            *(bf16x8*)(eb + 512) = ap1;
        }
        if (it2 < 3) {
#pragma unroll
            for (int k = 0; k < 4; ++k)
                *(bf16x8*)&Qw[w][1 - cur][srow][scoff + k * 8] = p[k];
        }
        // no barrier: Qw[w]/Ps[w] wave-private, DS ops in-order per wave
    }

#pragma unroll
    for (int nt = 0; nt < 4; ++nt) red[w * 4 + quad][nt * 16 + c] = lsum[nt];
    __syncthreads();
    if (t < 64) {
        float sum = 0.f;
#pragma unroll
        for (int r = 0; r < 16; ++r) sum += red[r][t];
        lpart[((size_t)s * Bn + b) * Nn + jbase + t] = sum;   // plain store
    }
}

// ---------------------------------------------------------------------------
// lscale: Vt[b][d][j] /= l[b][j]  in place (l = sum of 4 lparts).
// ---------------------------------------------------------------------------
__global__ __launch_bounds__(256) void lscale_kernel(
    short* __restrict__ Vt, const float* __restrict__ lpart)
{
    const int row = blockIdx.x;              // b*64 + d, 0..511
    const int b = row >> 6;
    const int t = threadIdx.x;
    const int j0 = t * 8;
    bf16x8 v = *(const bf16x8*)&Vt[(size_t)row * Nn + j0];
    float lv[8];
#pragma unroll
    for (int e = 0; e < 8; ++e) lv[e] = 0.f;
#pragma unroll
    for (int s = 0; s < 4; ++s) {
        const float* lp = &lpart[((size_t)s * Bn + b) * Nn + j0];
        const float4 a = ((const float4*)lp)[0];
        const float4 bb = ((const float4*)lp)[1];
        lv[0] += a.x;  lv[1] += a.y;  lv[2] += a.z;  lv[3] += a.w;
        lv[4] += bb.x; lv[5] += bb.y; lv[6] += bb.z; lv[7] += bb.w;
    }
    bf16x8 o;
#pragma unroll
    for (int e = 0; e < 8; ++e) o[e] = f2bf(bf2f(v[e]) / lv[e]);
    *(bf16x8*)&Vt[(size_t)row * Nn + j0] = o;
}

// ---------------------------------------------------------------------------
// K3: pure PV GEMM.  outp[s][i][d] = sum_{j in split s} E[i][j] V''[j][d].
// Grid (b, i-tile 64, j-split 4) = 1024.  A-frags DIRECT from frag-major Eb
// (coalesced 1KB wave-loads); V'' staged in LDS (dbuf, 1 barrier/tile).
// No exp, no S recompute, no bounce.  LDS = 18 KB.
// ---------------------------------------------------------------------------
__global__ __launch_bounds__(256) void attnout_kernel(
    const short* __restrict__ Eb, const short* __restrict__ Vt,
    float* __restrict__ outp)
{
    __shared__ __attribute__((aligned(16))) short Vs[2][64][PAD];

    const int t = threadIdx.x;
    const int w = t >> 6, l = t & 63;
    const int c = l & 15, quad = l >> 4;
    const int bid = blockIdx.x;
    const int b = bid >> 7, rem = bid & 127, it = rem >> 2, s = rem & 3;
    const int ibase = it * 64;
    const int f = it * 4 + w;                 // this wave's global i-frag
    const int r0 = t >> 2, cc = (t & 3) * 16;

    const short* ebase = &Eb[(((size_t)b * 128 + f) * 64 + s * 16) * 512 + l * 8];
    const short* vbase = &Vt[((size_t)b * DHn + r0) * Nn + s * 512 + cc];

    // stage tile 0
    *(bf16x8*)&Vs[0][r0][cc]     = *(const bf16x8*)vbase;
    *(bf16x8*)&Vs[0][r0][cc + 8] = *(const bf16x8*)(vbase + 8);
    bf16x8 ea0 = *(const bf16x8*)(ebase);
    bf16x8 ea1 = *(const bf16x8*)(ebase + 512);

    f32x4 acc[4];
#pragma unroll
    for (int dn = 0; dn < 4; ++dn) acc[dn] = (f32x4){0.f, 0.f, 0.f, 0.f};
    __syncthreads();

    for (int jj = 0; jj < 8; ++jj) {
        const int cur = jj & 1;
        bf16x8 pv0, pv1, pe0, pe1;
        if (jj < 7) {
            const short* pv = vbase + (jj + 1) * 64;
            pv0 = *(const bf16x8*)pv; pv1 = *(const bf16x8*)(pv + 8);
            pe0 = *(const bf16x8*)(ebase + (size_t)(jj * 2 + 2) * 512);
            pe1 = *(const bf16x8*)(ebase + (size_t)(jj * 2 + 3) * 512);
        }
#pragma unroll
        for (int dn = 0; dn < 4; ++dn) {
            const bf16x8 vb0 = *(const bf16x8*)&Vs[cur][dn * 16 + c][quad * 8];
            const bf16x8 vb1 = *(const bf16x8*)&Vs[cur][dn * 16 + c][32 + quad * 8];
            acc[dn] = __builtin_amdgcn_mfma_f32_16x16x32_bf16(ea0, vb0, acc[dn], 0, 0, 0);
            acc[dn] = __builtin_amdgcn_mfma_f32_16x16x32_bf16(ea1, vb1, acc[dn], 0, 0, 0);
        }
        if (jj < 7) {
            *(bf16x8*)&Vs[1 - cur][r0][cc]     = pv0;
            *(bf16x8*)&Vs[1 - cur][r0][cc + 8] = pv1;
            ea0 = pe0; ea1 = pe1;
        }
        __syncthreads();
    }

    float* op = outp + (size_t)s * (Bn * Nn * DHn) + ((size_t)b * Nn + ibase) * DHn;
#pragma unroll
    for (int dn = 0; dn < 4; ++dn)
#pragma unroll
        for (int r = 0; r < 4; ++r)
            op[(w * 16 + quad * 4 + r) * DHn + dn * 16 + c] = acc[dn][r];
}

// ---------------------------------------------------------------------------
// Reduce the 4 partial buffers into out.
// ---------------------------------------------------------------------------
__global__ __launch_bounds__(256) void outreduce_kernel(
    const float* __restrict__ outp, float* __restrict__ out)
{
    const int id = blockIdx.x * 256 + threadIdx.x;   // 262144 float4
    const float4* p = (const float4*)outp;
    const float4 a = p[id];
    const float4 b = p[id + 262144];
    const float4 c = p[id + 2 * 262144];
    const float4 d = p[id + 3 * 262144];
    float4 r;
    r.x = a.x + b.x + c.x + d.x;
    r.y = a.y + b.y + c.y + d.y;
    r.z = a.z + b.z + c.z + d.z;
    r.w = a.w + b.w + c.w + d.w;
    ((float4*)out)[id] = r;
}

// ---------------------------------------------------------------------------
extern "C" void kernel_launch(void* const* d_in, const int* in_sizes, int n_in,
                              void* d_out, int out_size, void* d_ws, size_t ws_size,
                              hipStream_t stream)
{
    const float* x  = (const float*)d_in[0];
    const float* Wq = (const float*)d_in[1];
    const float* bq = (const float*)d_in[2];
    const float* Wk = (const float*)d_in[3];
    const float* bk = (const float*)d_in[4];
    const float* Wv = (const float*)d_in[5];
    const float* bv = (const float*)d_in[6];
    float* out = (float*)d_out;

    char* ws = (char*)d_ws;
    short* Qb    = (short*)(ws);                                   // 2 MB
    short* Kb    = (short*)(ws + (size_t)(1 << 21));               // 2 MB
    short* Vt    = (short*)(ws + (size_t)(2 << 21));               // 2 MB [b][d][j]
    short* Wtf   = (short*)(ws + (size_t)(3 << 21));               // 384 KB (frag-major)
    float* lpart = (float*)(ws + (size_t)(3 << 21) + (1 << 19));   // 256 KB (4 splits)
    short* Eb    = (short*)(ws + (size_t)(8 << 20));               // 64 MB (A-frag-major E)
    float* outp  = (float*)(ws + (size_t)(80 << 20));              // 16 MB (4 partials)

    wt_kernel<<<dim3(192), dim3(128), 0, stream>>>(Wq, Wk, Wv, Wtf);
    qkv_kernel<<<dim3(512), dim3(256), 0, stream>>>(x, Wtf, bq, bk, bv, Qb, Kb, Vt);
    colsum_kernel<<<dim3(1024), dim3(256), 0, stream>>>(Qb, Kb, lpart, Eb);
    lscale_kernel<<<dim3(512), dim3(256), 0, stream>>>(Vt, lpart);
    attnout_kernel<<<dim3(1024), dim3(256), 0, stream>>>(Eb, Vt, outp);
    outreduce_kernel<<<dim3(1024), dim3(256), 0, stream>>>(outp, out);
}